// Round 1
// baseline (151.058 us; speedup 1.0000x reference)
//
#include <hip/hip_runtime.h>

#define L_SEQ 4096
#define DMODEL 256
#define DH 64
#define NKB 16   // key blocks (of 64) per workgroup: 4096 / 64 / ksplit(4)

typedef __attribute__((ext_vector_type(8))) __bf16 bf16x8;
typedef __attribute__((ext_vector_type(4))) float f32x4;
typedef __attribute__((ext_vector_type(16))) float f32x16;
typedef __attribute__((ext_vector_type(8))) unsigned short ushort8v;
typedef __attribute__((ext_vector_type(4))) unsigned short ushort4v;
typedef __attribute__((ext_vector_type(2))) unsigned int uint2v;
typedef __attribute__((ext_vector_type(4))) unsigned int uint4v;

__device__ __forceinline__ unsigned short f2bf(float f) {
  unsigned u = __builtin_bit_cast(unsigned, f);
  u += 0x7fffu + ((u >> 16) & 1u);
  return (unsigned short)(u >> 16);
}
__device__ __forceinline__ float bf2f(unsigned short h) {
  unsigned u = ((unsigned)h) << 16;
  return __builtin_bit_cast(float, u);
}
__device__ __forceinline__ bf16x8 ld_frag(const unsigned short* p) {
  return __builtin_bit_cast(bf16x8, *(const ushort8v*)p);
}
// pack 2 f32 -> 2 bf16 (RNE) in one VALU op (no builtin on gfx950; guide T12)
__device__ __forceinline__ unsigned cvtpk(float lo, float hi) {
  unsigned r;
  asm("v_cvt_pk_bf16_f32 %0, %1, %2" : "=v"(r) : "v"(lo), "v"(hi));
  return r;
}
// a.hi32lanes <-> b.lo32lanes (v_permlane32_swap_b32, gfx950)
__device__ __forceinline__ void plswap(unsigned& a, unsigned& b) {
  asm("v_permlane32_swap_b32 %0, %1" : "+v"(a), "+v"(b));
}

// ---- 1. q [B,C,L] fp32 -> xbf [B*L, C] bf16; blocks >=512 convert weights ----
__global__ __launch_bounds__(256) void k_transpose(const float* __restrict__ q,
                                                   unsigned short* __restrict__ xbf,
                                                   const float* __restrict__ w,
                                                   const float* __restrict__ fcw,
                                                   unsigned short* __restrict__ wbf,
                                                   unsigned short* __restrict__ fcwbf) {
  int bx = blockIdx.x;
  int t = threadIdx.x;
  if (bx >= 512) {   // weight conversion tail
    int i = ((bx - 512) * 256 + t) * 4;
    float4 a = *(const float4*)(w + i);
    float4 b = *(const float4*)(fcw + i);
    ushort4v av = {f2bf(a.x), f2bf(a.y), f2bf(a.z), f2bf(a.w)};
    ushort4v bv = {f2bf(b.x), f2bf(b.y), f2bf(b.z), f2bf(b.w)};
    *(ushort4v*)(wbf + i) = av;
    *(ushort4v*)(fcwbf + i) = bv;
    return;
  }
  __shared__ float T[64 * 65];
  int b = bx >> 8, rest = bx & 255;
  int ct = rest >> 6, lt = rest & 63;
#pragma unroll
  for (int it = 0; it < 4; ++it) {
    int i = (t >> 4) + it * 16;
    int j0 = (t & 15) * 4;
    float4 v = *(const float4*)(q + ((size_t)(b * 256 + ct * 64 + i)) * 4096 + lt * 64 + j0);
    T[i * 65 + j0 + 0] = v.x;
    T[i * 65 + j0 + 1] = v.y;
    T[i * 65 + j0 + 2] = v.z;
    T[i * 65 + j0 + 3] = v.w;
  }
  __syncthreads();
#pragma unroll
  for (int it = 0; it < 2; ++it) {
    int l = (t >> 3) + it * 32;
    int c0 = (t & 7) * 8;
    ushort8v o;
#pragma unroll
    for (int k = 0; k < 8; ++k) o[k] = f2bf(T[(c0 + k) * 65 + l]);
    *(ushort8v*)(xbf + ((size_t)(b * 4096 + lt * 64 + l)) * 256 + ct * 64 + c0) = o;
  }
}

// ---- 2. QKV GEMM -> Qh [p][l][d] and QhT [p][d][l] (LDS-bounced stores) ----
#define KP2 136
__global__ __launch_bounds__(256) void k_qkv(const unsigned short* __restrict__ xbf,
                                             const unsigned short* __restrict__ wbf,
                                             unsigned short* __restrict__ Qh,
                                             unsigned short* __restrict__ QhT) {
  __shared__ unsigned short As[64 * KP2];
  __shared__ unsigned short Bs[64 * KP2];
  int bx = blockIdx.x;
  int mtile = bx >> 2, h = bx & 3;
  int m0 = mtile * 64;
  int b = m0 >> 12, l0 = m0 & 4095;
  int t = threadIdx.x;
  int wv = t >> 6, lane = t & 63, g = lane >> 4, ln = lane & 15;
  f32x4 acc[4] = {};
  for (int kb = 0; kb < 2; ++kb) {
#pragma unroll
    for (int it = 0; it < 4; ++it) {
      int idx = t + it * 256;
      int row = idx >> 4;
      int c0 = (idx & 15) * 8;
      *(ushort8v*)(As + row * KP2 + c0) =
          *(const ushort8v*)(xbf + (size_t)(m0 + row) * 256 + kb * 128 + c0);
      *(ushort8v*)(Bs + row * KP2 + c0) =
          *(const ushort8v*)(wbf + (size_t)(h * 64 + row) * 256 + kb * 128 + c0);
    }
    __syncthreads();
#pragma unroll
    for (int kc = 0; kc < 4; ++kc) {
      bf16x8 a = ld_frag(As + (wv * 16 + ln) * KP2 + kc * 32 + g * 8);
#pragma unroll
      for (int tn = 0; tn < 4; ++tn) {
        bf16x8 bb = ld_frag(Bs + (tn * 16 + ln) * KP2 + kc * 32 + g * 8);
        acc[tn] = __builtin_amdgcn_mfma_f32_16x16x32_bf16(a, bb, acc[tn], 0, 0, 0);
      }
    }
    __syncthreads();
  }
  size_t pbase = (size_t)(b * 4 + h);
  // ---- epilogue: bounce tiles through LDS, then dense 16-B stores ----
#pragma unroll
  for (int tn = 0; tn < 4; ++tn) {
#pragma unroll
    for (int r = 0; r < 4; ++r) {
      int lrow = wv * 16 + g * 4 + r;
      int d = tn * 16 + ln;
      unsigned short bv = f2bf(acc[tn][r]);
      As[lrow * 64 + (((d >> 3) ^ (lrow & 7)) * 8) + (d & 7)] = bv;
      Bs[d * 64 + (((lrow >> 3) ^ (d & 7)) * 8) + (lrow & 7)] = bv;
    }
  }
#pragma unroll
  for (int s = 0; s < 2; ++s) {
    int flat = s * 64 + lane;
    int lrow = wv * 16 + (flat >> 3);
    int c8 = lane & 7;
    ushort8v v = *(const ushort8v*)(As + lrow * 64 + ((c8 ^ (lrow & 7)) * 8));
    *(ushort8v*)(Qh + (pbase * L_SEQ + l0 + lrow) * DH + c8 * 8) = v;
  }
  __syncthreads();
#pragma unroll
  for (int s = 0; s < 2; ++s) {
    int flat = s * 256 + t;
    int drow = flat >> 3;
    int c8 = t & 7;
    ushort8v v = *(const ushort8v*)(Bs + drow * 64 + ((c8 ^ (drow & 7)) * 8));
    *(ushort8v*)(QhT + (pbase * DH + drow) * L_SEQ + l0 + c8 * 8) = v;
  }
}

// ---- 3. flash attention, 32x32x16 MFMA, in-register softmax (T12), ks=4 ----
// S^T = K Q^T: A=K rows (m=key), B=Q cols (n=q). D: col=lane&31=q,
// row=(reg&3)+8*(reg>>2)+4*(lane>>5)=key. So each lane owns ONE q and 16 keys.
// cvt_pk pairs + 4x permlane32_swap rebuild P directly in the PV B-operand
// layout (n=q=lane&31, k=keys, lo-lane keys c*16+0..7 / hi-lane +8..15) —
// no Pb LDS bounce. PV computed as O^T = V^T P (A = Vt [d][key] tile as-is).
// O^T D-layout: col=q, rows=4-contiguous-d groups -> cvt_pk + direct 8B
// nontemporal stores, no epilogue LDS bounce.
// K/V double-buffered: ONE barrier per key block (write-regs, barrier,
// prefetch next, compute). launch_bounds(256,2): grid 512 = 2 wg/CU.
__global__ __launch_bounds__(256, 2) void k_attn(const unsigned short* __restrict__ Qh,
                                                 const unsigned short* __restrict__ QhT,
                                                 unsigned short* __restrict__ Opart,
                                                 float* __restrict__ Lpart) {
  __shared__ unsigned short smem[4 * 4096];  // K0 V0 K1 V1, 8KB each, 32 KB
  int bx = blockIdx.x;
  int p = bx & 7;
  int u = bx >> 3;
  int qsup = u & 15, ks = u >> 4;
  int t = threadIdx.x;
  int wv = t >> 6, lane = t & 63, ln = lane & 31, hi = lane >> 5;
  const unsigned short* Qp = Qh + (size_t)p * L_SEQ * DH;
  const unsigned short* QTp = QhT + (size_t)p * DH * L_SEQ;
  int q0 = qsup * 256;
  int qw = q0 + wv * 64;  // this wave's 64 q rows

  // Q fragments (B operand, whole loop): q = qw+qt*32+ln, d = kq*16+hi*8
  bf16x8 aQ[2][4];
#pragma unroll
  for (int qt = 0; qt < 2; ++qt)
#pragma unroll
    for (int kq = 0; kq < 4; ++kq)
      aQ[qt][kq] = ld_frag(Qp + (size_t)(qw + qt * 32 + ln) * DH + kq * 16 + hi * 8);

  f32x16 oacc[2][2] = {};       // [dt][qt], O^T fragments
  float lacc[2] = {0.f, 0.f};   // [qt], per-lane partial l (half the keys)

  // staging addresses: rows srow, 8-chunk scol, 16B XOR swizzle by row&7
  int srow0 = t >> 3, scol = t & 7;
  int srow1 = srow0 + 32;
  int sdst0 = srow0 * 64 + ((scol ^ (srow0 & 7)) * 8);
  int sdst1 = srow1 * 64 + ((scol ^ (srow1 & 7)) * 8);

  ushort8v kreg0, kreg1, vreg0, vreg1;
  {
    int kbase = (ks * NKB) * 64;
    kreg0 = *(const ushort8v*)(Qp + (size_t)(kbase + srow0) * DH + scol * 8);
    kreg1 = *(const ushort8v*)(Qp + (size_t)(kbase + srow1) * DH + scol * 8);
    vreg0 = *(const ushort8v*)(QTp + (size_t)srow0 * L_SEQ + kbase + scol * 8);
    vreg1 = *(const ushort8v*)(QTp + (size_t)srow1 * L_SEQ + kbase + scol * 8);
  }

  for (int kb = 0; kb < NKB; ++kb) {
    unsigned short* Kc = smem + (kb & 1) * 8192;
    unsigned short* Vc = Kc + 4096;
    // write buf[kb&1]: safe — its last readers (compute kb-2) are gated by
    // barrier(kb-1), which every wave passed before reaching this write.
    *(ushort8v*)(Kc + sdst0) = kreg0;
    *(ushort8v*)(Kc + sdst1) = kreg1;
    *(ushort8v*)(Vc + sdst0) = vreg0;
    *(ushort8v*)(Vc + sdst1) = vreg1;
    __syncthreads();
    if (kb + 1 < NKB) {  // issue next tile's loads; land during compute
      int kbase = (ks * NKB + kb + 1) * 64;
      kreg0 = *(const ushort8v*)(Qp + (size_t)(kbase + srow0) * DH + scol * 8);
      kreg1 = *(const ushort8v*)(Qp + (size_t)(kbase + srow1) * DH + scol * 8);
      vreg0 = *(const ushort8v*)(QTp + (size_t)srow0 * L_SEQ + kbase + scol * 8);
      vreg1 = *(const ushort8v*)(QTp + (size_t)srow1 * L_SEQ + kbase + scol * 8);
    }
#pragma unroll
    for (int mt = 0; mt < 2; ++mt) {
      int key = mt * 32 + ln;
      bf16x8 aK[4];
#pragma unroll
      for (int kq = 0; kq < 4; ++kq)
        aK[kq] = ld_frag(Kc + key * 64 + (((kq * 2 + hi) ^ (key & 7)) * 8));
      bf16x8 pf[2][2];  // [qt][16-key chunk]
#pragma unroll
      for (int qt = 0; qt < 2; ++qt) {
        f32x16 s = {};
#pragma unroll
        for (int kq = 0; kq < 4; ++kq)
          s = __builtin_amdgcn_mfma_f32_32x32x16_bf16(aK[kq], aQ[qt][kq], s, 0, 0, 0);
        // fixed-max softmax: p = exp(s/8 - 16); all 16 values same q
        float pv[16];
#pragma unroll
        for (int r = 0; r < 16; ++r) pv[r] = __expf(fmaf(s[r], 0.125f, -16.0f));
        lacc[qt] += (((pv[0] + pv[1]) + (pv[2] + pv[3])) + ((pv[4] + pv[5]) + (pv[6] + pv[7]))) +
                    (((pv[8] + pv[9]) + (pv[10] + pv[11])) + ((pv[12] + pv[13]) + (pv[14] + pv[15])));
        // regs (0..15) -> keys (r&3)+8*(r>>2)+4*hi; pack + swap into B-frags
        unsigned w0 = cvtpk(pv[0], pv[1]), w1 = cvtpk(pv[2], pv[3]);
        unsigned w2 = cvtpk(pv[4], pv[5]), w3 = cvtpk(pv[6], pv[7]);
        unsigned w4 = cvtpk(pv[8], pv[9]), w5 = cvtpk(pv[10], pv[11]);
        unsigned w6 = cvtpk(pv[12], pv[13]), w7 = cvtpk(pv[14], pv[15]);
        plswap(w0, w2);  // after: w0 = keys{lo:0,1 | hi:8,9}, w2 = {lo:4,5 | hi:12,13}
        plswap(w1, w3);  //        w1 = {lo:2,3 | hi:10,11}, w3 = {lo:6,7 | hi:14,15}
        plswap(w4, w6);  // same for keys 16..31 (chunk 1)
        plswap(w5, w7);
        uint4v c0 = {w0, w1, w2, w3};
        uint4v c1 = {w4, w5, w6, w7};
        pf[qt][0] = __builtin_bit_cast(bf16x8, c0);
        pf[qt][1] = __builtin_bit_cast(bf16x8, c1);
      }
      // ---- O^T += V^T P for this mt's 32 keys ----
#pragma unroll
      for (int dt = 0; dt < 2; ++dt) {
        int d = dt * 32 + ln;
        bf16x8 vf[2];
#pragma unroll
        for (int c = 0; c < 2; ++c)
          vf[c] = ld_frag(Vc + d * 64 + (((mt * 4 + c * 2 + hi) ^ (d & 7)) * 8));
#pragma unroll
        for (int qt = 0; qt < 2; ++qt)
#pragma unroll
          for (int c = 0; c < 2; ++c)
            oacc[dt][qt] = __builtin_amdgcn_mfma_f32_32x32x16_bf16(vf[c], pf[qt][c], oacc[dt][qt], 0, 0, 0);
      }
    }
  }
  // l: lanes l and l+32 hold same q, disjoint key halves
#pragma unroll
  for (int qt = 0; qt < 2; ++qt) lacc[qt] += __shfl_xor(lacc[qt], 32, 64);
  size_t pq = (size_t)(ks * 8 + p) * L_SEQ;
  if (lane < 32) {
    __builtin_nontemporal_store(lacc[0], &Lpart[pq + qw + ln]);
    __builtin_nontemporal_store(lacc[1], &Lpart[pq + qw + 32 + ln]);
  }
  // O^T epilogue: lane owns q = qw+qt*32+ln; regs g8*4+j -> d = g8*8+4*hi+j
  // (4 contiguous d per reg group) -> cvt_pk pairs -> direct 8B stores [q][d]
#pragma unroll
  for (int dt = 0; dt < 2; ++dt)
#pragma unroll
    for (int qt = 0; qt < 2; ++qt) {
      size_t rb = (pq + qw + qt * 32 + ln) * DH + dt * 32 + hi * 4;
#pragma unroll
      for (int g8 = 0; g8 < 4; ++g8) {
        uint2v wv2 = {cvtpk(oacc[dt][qt][g8 * 4 + 0], oacc[dt][qt][g8 * 4 + 1]),
                      cvtpk(oacc[dt][qt][g8 * 4 + 2], oacc[dt][qt][g8 * 4 + 3])};
        __builtin_nontemporal_store(wv2, (uint2v*)(Opart + rb + g8 * 8));
      }
    }
}

// ---- 4. FC GEMM (fused ks-merge in A-staging) + bias + residual + LayerNorm ----
#define CP 72
__global__ __launch_bounds__(256) void k_fc(const unsigned short* __restrict__ Opart,
                                            const float* __restrict__ Lpart,
                                            const unsigned short* __restrict__ fcwbf,
                                            const float* __restrict__ qres,
                                            const float* __restrict__ fcb,
                                            const float* __restrict__ lng,
                                            const float* __restrict__ lnb,
                                            float* __restrict__ out) {
  __shared__ unsigned short As[32 * CP];
  __shared__ unsigned short Bs[256 * CP];
  __shared__ float redS[4][32], redQ[4][32], muA[32], rsA[32];
  int bx = blockIdx.x;
  int m0 = bx * 32;
  int b = m0 >> 12, lpart = m0 & 4095;
  int t = threadIdx.x;
  int wv = t >> 6, lane = t & 63, g = lane >> 4, ln = lane & 15;
  f32x4 acc[2][4] = {};
  for (int kb = 0; kb < 4; ++kb) {   // kb == head index for A-staging
    {
      int row = t >> 3, c0 = (t & 7) * 8;
      int q = lpart + row;
      int p = b * 4 + kb;
      float lsum = __builtin_nontemporal_load(&Lpart[(size_t)(0 * 8 + p) * L_SEQ + q]) +
                   __builtin_nontemporal_load(&Lpart[(size_t)(1 * 8 + p) * L_SEQ + q]) +
                   __builtin_nontemporal_load(&Lpart[(size_t)(2 * 8 + p) * L_SEQ + q]) +
                   __builtin_nontemporal_load(&Lpart[(size_t)(3 * 8 + p) * L_SEQ + q]);
      float inv = 1.0f / lsum;
      float a8[8] = {0.f, 0.f, 0.f, 0.f, 0.f, 0.f, 0.f, 0.f};
#pragma unroll
      for (int ksp = 0; ksp < 4; ++ksp) {
        ushort8v v = __builtin_nontemporal_load(
            (const ushort8v*)(Opart + ((size_t)(ksp * 8 + p) * L_SEQ + q) * DH + c0));
#pragma unroll
        for (int j = 0; j < 8; ++j) a8[j] += bf2f(v[j]);
      }
      ushort8v o;
#pragma unroll
      for (int j = 0; j < 8; ++j) o[j] = f2bf(a8[j] * inv);
      *(ushort8v*)(As + row * CP + c0) = o;
    }
#pragma unroll
    for (int it = 0; it < 8; ++it) {
      int idx = t + it * 256;
      int row = idx >> 3, c0 = (idx & 7) * 8;
      *(ushort8v*)(Bs + row * CP + c0) =
          *(const ushort8v*)(fcwbf + (size_t)row * 256 + kb * 64 + c0);
    }
    __syncthreads();
#pragma unroll
    for (int kc = 0; kc < 2; ++kc) {
      bf16x8 a[2], bb[4];
#pragma unroll
      for (int mt = 0; mt < 2; ++mt) a[mt] = ld_frag(As + (mt * 16 + ln) * CP + kc * 32 + g * 8);
#pragma unroll
      for (int tn = 0; tn < 4; ++tn) bb[tn] = ld_frag(Bs + (wv * 64 + tn * 16 + ln) * CP + kc * 32 + g * 8);
#pragma unroll
      for (int mt = 0; mt < 2; ++mt)
#pragma unroll
        for (int tn = 0; tn < 4; ++tn)
          acc[mt][tn] = __builtin_amdgcn_mfma_f32_16x16x32_bf16(a[mt], bb[tn], acc[mt][tn], 0, 0, 0);
    }
    __syncthreads();
  }
  float fb[4], lg[4], lb[4];
#pragma unroll
  for (int tn = 0; tn < 4; ++tn) {
    int o = wv * 64 + tn * 16 + ln;
    fb[tn] = fcb[o]; lg[tn] = lng[o]; lb[tn] = lnb[o];
  }
#pragma unroll
  for (int mt = 0; mt < 2; ++mt) {
    float ps[4] = {0.f, 0.f, 0.f, 0.f}, pq2[4] = {0.f, 0.f, 0.f, 0.f};
#pragma unroll
    for (int tn = 0; tn < 4; ++tn) {
      int o = wv * 64 + tn * 16 + ln;
      float4 res = *(const float4*)(qres + ((size_t)(b * 256 + o)) * 4096 + lpart + mt * 16 + g * 4);
      float rv[4] = {res.x, res.y, res.z, res.w};
#pragma unroll
      for (int r = 0; r < 4; ++r) {
        float v = acc[mt][tn][r] + fb[tn] + rv[r];
        acc[mt][tn][r] = v;
        ps[r] += v;
        pq2[r] += v * v;
      }
    }
#pragma unroll
    for (int r = 0; r < 4; ++r) {
      float s = ps[r], q2 = pq2[r];
#pragma unroll
      for (int off = 1; off < 16; off <<= 1) {
        s += __shfl_xor(s, off, 64);
        q2 += __shfl_xor(q2, off, 64);
      }
      if (ln == 0) {
        int row = mt * 16 + g * 4 + r;
        redS[wv][row] = s;
        redQ[wv][row] = q2;
      }
    }
  }
  __syncthreads();
  if (t < 32) {
    float s = redS[0][t] + redS[1][t] + redS[2][t] + redS[3][t];
    float q2 = redQ[0][t] + redQ[1][t] + redQ[2][t] + redQ[3][t];
    float mu = s * (1.f / 256.f);
    float var = q2 * (1.f / 256.f) - mu * mu;
    muA[t] = mu;
    rsA[t] = rsqrtf(var + 1e-5f);
  }
  __syncthreads();
#pragma unroll
  for (int mt = 0; mt < 2; ++mt) {
#pragma unroll
    for (int r = 0; r < 4; ++r) {
      int row = mt * 16 + g * 4 + r;
      float mu = muA[row], rs = rsA[row];
#pragma unroll
      for (int tn = 0; tn < 4; ++tn) {
        int o = wv * 64 + tn * 16 + ln;
        out[(size_t)(m0 + row) * 256 + o] = (acc[mt][tn][r] - mu) * rs * lg[tn] + lb[tn];
      }
    }
  }
}

extern "C" void kernel_launch(void* const* d_in, const int* in_sizes, int n_in,
                              void* d_out, int out_size, void* d_ws, size_t ws_size,
                              hipStream_t stream) {
  const float* q = (const float*)d_in[0];
  const float* w_qkv = (const float*)d_in[1];
  const float* fc_w = (const float*)d_in[2];
  const float* fc_b = (const float*)d_in[3];
  const float* ln_g = (const float*)d_in[4];
  const float* ln_b = (const float*)d_in[5];
  float* out = (float*)d_out;

  unsigned short* wbf = (unsigned short*)d_ws;   // 65536
  unsigned short* fcwbf = wbf + 65536;           // 65536
  unsigned short* xbf = fcwbf + 65536;           // 8192*256
  unsigned short* Qh = xbf + 2097152;            // [p][l][d]
  unsigned short* QhT = Qh + 2097152;            // [p][d][l]
  unsigned short* Opart = QhT + 2097152;         // [ks][p][q][d] bf16, 4*2M
  float* Lpart = (float*)(Opart + 8388608);      // [ks][p][q] fp32
  // total ws use: ~30.1 MB

  k_transpose<<<dim3(576), dim3(256), 0, stream>>>(q, xbf, w_qkv, fc_w, wbf, fcwbf);
  k_qkv<<<dim3(512), dim3(256), 0, stream>>>(xbf, wbf, Qh, QhT);
  k_attn<<<dim3(512), dim3(256), 0, stream>>>(Qh, QhT, Opart, Lpart);
  k_fc<<<dim3(256), dim3(256), 0, stream>>>(Opart, Lpart, fcwbf, q, fc_b, ln_g, ln_b, out);
}

// Round 3
// 133.434 us; speedup vs baseline: 1.1321x; 1.1321x over previous
//
#include <hip/hip_runtime.h>

#define L_SEQ 4096
#define DMODEL 256
#define DH 64
#define NKB 16   // key blocks (of 64) per workgroup: 4096 / 64 / ksplit(4)

typedef __attribute__((ext_vector_type(8))) __bf16 bf16x8;
typedef __attribute__((ext_vector_type(4))) float f32x4;
typedef __attribute__((ext_vector_type(16))) float f32x16;
typedef __attribute__((ext_vector_type(8))) unsigned short ushort8v;
typedef __attribute__((ext_vector_type(4))) unsigned short ushort4v;
typedef __attribute__((ext_vector_type(2))) unsigned int uint2v;
typedef __attribute__((ext_vector_type(4))) unsigned int uint4v;

__device__ __forceinline__ unsigned short f2bf(float f) {
  unsigned u = __builtin_bit_cast(unsigned, f);
  u += 0x7fffu + ((u >> 16) & 1u);
  return (unsigned short)(u >> 16);
}
__device__ __forceinline__ float bf2f(unsigned short h) {
  unsigned u = ((unsigned)h) << 16;
  return __builtin_bit_cast(float, u);
}
__device__ __forceinline__ bf16x8 ld_frag(const unsigned short* p) {
  return __builtin_bit_cast(bf16x8, *(const ushort8v*)p);
}
// pack 2 f32 -> 2 bf16 (RNE) in one VALU op (no builtin on gfx950; guide T12)
__device__ __forceinline__ unsigned cvtpk(float lo, float hi) {
  unsigned r;
  asm("v_cvt_pk_bf16_f32 %0, %1, %2" : "=v"(r) : "v"(lo), "v"(hi));
  return r;
}
// a.hi32lanes <-> b.lo32lanes (v_permlane32_swap_b32, gfx950)
__device__ __forceinline__ void plswap(unsigned& a, unsigned& b) {
  asm("v_permlane32_swap_b32 %0, %1" : "+v"(a), "+v"(b));
}

// ---- 1. q [B,C,L] fp32 -> xbf [B*L, C] bf16; blocks >=512 convert weights ----
__global__ __launch_bounds__(256) void k_transpose(const float* __restrict__ q,
                                                   unsigned short* __restrict__ xbf,
                                                   const float* __restrict__ w,
                                                   const float* __restrict__ fcw,
                                                   unsigned short* __restrict__ wbf,
                                                   unsigned short* __restrict__ fcwbf) {
  int bx = blockIdx.x;
  int t = threadIdx.x;
  if (bx >= 512) {   // weight conversion tail
    int i = ((bx - 512) * 256 + t) * 4;
    float4 a = *(const float4*)(w + i);
    float4 b = *(const float4*)(fcw + i);
    ushort4v av = {f2bf(a.x), f2bf(a.y), f2bf(a.z), f2bf(a.w)};
    ushort4v bv = {f2bf(b.x), f2bf(b.y), f2bf(b.z), f2bf(b.w)};
    *(ushort4v*)(wbf + i) = av;
    *(ushort4v*)(fcwbf + i) = bv;
    return;
  }
  __shared__ float T[64 * 65];
  int b = bx >> 8, rest = bx & 255;
  int ct = rest >> 6, lt = rest & 63;
#pragma unroll
  for (int it = 0; it < 4; ++it) {
    int i = (t >> 4) + it * 16;
    int j0 = (t & 15) * 4;
    float4 v = *(const float4*)(q + ((size_t)(b * 256 + ct * 64 + i)) * 4096 + lt * 64 + j0);
    T[i * 65 + j0 + 0] = v.x;
    T[i * 65 + j0 + 1] = v.y;
    T[i * 65 + j0 + 2] = v.z;
    T[i * 65 + j0 + 3] = v.w;
  }
  __syncthreads();
#pragma unroll
  for (int it = 0; it < 2; ++it) {
    int l = (t >> 3) + it * 32;
    int c0 = (t & 7) * 8;
    ushort8v o;
#pragma unroll
    for (int k = 0; k < 8; ++k) o[k] = f2bf(T[(c0 + k) * 65 + l]);
    *(ushort8v*)(xbf + ((size_t)(b * 4096 + lt * 64 + l)) * 256 + ct * 64 + c0) = o;
  }
}

// ---- 2. QKV GEMM -> Qh [p][l][d] and QhT [p][d][l] (LDS-bounced stores) ----
#define KP2 136
__global__ __launch_bounds__(256) void k_qkv(const unsigned short* __restrict__ xbf,
                                             const unsigned short* __restrict__ wbf,
                                             unsigned short* __restrict__ Qh,
                                             unsigned short* __restrict__ QhT) {
  __shared__ unsigned short As[64 * KP2];
  __shared__ unsigned short Bs[64 * KP2];
  int bx = blockIdx.x;
  int mtile = bx >> 2, h = bx & 3;
  int m0 = mtile * 64;
  int b = m0 >> 12, l0 = m0 & 4095;
  int t = threadIdx.x;
  int wv = t >> 6, lane = t & 63, g = lane >> 4, ln = lane & 15;
  f32x4 acc[4] = {};
  for (int kb = 0; kb < 2; ++kb) {
#pragma unroll
    for (int it = 0; it < 4; ++it) {
      int idx = t + it * 256;
      int row = idx >> 4;
      int c0 = (idx & 15) * 8;
      *(ushort8v*)(As + row * KP2 + c0) =
          *(const ushort8v*)(xbf + (size_t)(m0 + row) * 256 + kb * 128 + c0);
      *(ushort8v*)(Bs + row * KP2 + c0) =
          *(const ushort8v*)(wbf + (size_t)(h * 64 + row) * 256 + kb * 128 + c0);
    }
    __syncthreads();
#pragma unroll
    for (int kc = 0; kc < 4; ++kc) {
      bf16x8 a = ld_frag(As + (wv * 16 + ln) * KP2 + kc * 32 + g * 8);
#pragma unroll
      for (int tn = 0; tn < 4; ++tn) {
        bf16x8 bb = ld_frag(Bs + (tn * 16 + ln) * KP2 + kc * 32 + g * 8);
        acc[tn] = __builtin_amdgcn_mfma_f32_16x16x32_bf16(a, bb, acc[tn], 0, 0, 0);
      }
    }
    __syncthreads();
  }
  size_t pbase = (size_t)(b * 4 + h);
  // ---- epilogue: bounce tiles through LDS, then dense 16-B stores ----
#pragma unroll
  for (int tn = 0; tn < 4; ++tn) {
#pragma unroll
    for (int r = 0; r < 4; ++r) {
      int lrow = wv * 16 + g * 4 + r;
      int d = tn * 16 + ln;
      unsigned short bv = f2bf(acc[tn][r]);
      As[lrow * 64 + (((d >> 3) ^ (lrow & 7)) * 8) + (d & 7)] = bv;
      Bs[d * 64 + (((lrow >> 3) ^ (d & 7)) * 8) + (lrow & 7)] = bv;
    }
  }
#pragma unroll
  for (int s = 0; s < 2; ++s) {
    int flat = s * 64 + lane;
    int lrow = wv * 16 + (flat >> 3);
    int c8 = lane & 7;
    ushort8v v = *(const ushort8v*)(As + lrow * 64 + ((c8 ^ (lrow & 7)) * 8));
    *(ushort8v*)(Qh + (pbase * L_SEQ + l0 + lrow) * DH + c8 * 8) = v;
  }
  __syncthreads();
#pragma unroll
  for (int s = 0; s < 2; ++s) {
    int flat = s * 256 + t;
    int drow = flat >> 3;
    int c8 = t & 7;
    ushort8v v = *(const ushort8v*)(Bs + drow * 64 + ((c8 ^ (drow & 7)) * 8));
    *(ushort8v*)(QhT + (pbase * DH + drow) * L_SEQ + l0 + c8 * 8) = v;
  }
}

// ---- 3. flash attention, 32x32x16 MFMA, in-register softmax, q-split x2 ----
// R1 (passed): latency-bound, 2 wg/CU, MfmaUtil 22% == FLOP floor. R2 bundled
// KSN=8 + launch_bounds(256,4) + new epilogue and FAILED; this round isolates:
// keep R1's verified epilogue pattern + layout + bounds(256,2), and raise
// occupancy by halving the per-wave q-tile instead (32 q/wave, 128 q/block,
// grid 1024 = 8p x 32qsup x 4ks). Every line is the qt=0 slice of R1's
// passing code. Registers: oacc 64->32, aQ 32->16 => natural combined count
// ~130 => 3+ wg/CU without coercing the allocator.
// Stores are PLAIN (not nontemporal): R1's 8B nt scatters evicted partial
// lines (WRITE_SIZE 58.8 MB vs 16.7 MB data); cached stores let L2 assemble.
__global__ __launch_bounds__(256, 2) void k_attn(const unsigned short* __restrict__ Qh,
                                                 const unsigned short* __restrict__ QhT,
                                                 unsigned short* __restrict__ Opart,
                                                 float* __restrict__ Lpart) {
  __shared__ unsigned short smem[4 * 4096];  // K0 V0 K1 V1, 8KB each, 32 KB
  int bx = blockIdx.x;
  int p = bx & 7;
  int u = bx >> 3;
  int qsup = u & 31, ks = u >> 5;
  int t = threadIdx.x;
  int wv = t >> 6, lane = t & 63, ln = lane & 31, hi = lane >> 5;
  const unsigned short* Qp = Qh + (size_t)p * L_SEQ * DH;
  const unsigned short* QTp = QhT + (size_t)p * DH * L_SEQ;
  int q0 = qsup * 128;
  int qw = q0 + wv * 32;  // this wave's 32 q rows

  // Q fragments (B operand, whole loop): q = qw+ln, d = kq*16+hi*8
  bf16x8 aQ[4];
#pragma unroll
  for (int kq = 0; kq < 4; ++kq)
    aQ[kq] = ld_frag(Qp + (size_t)(qw + ln) * DH + kq * 16 + hi * 8);

  f32x16 oacc[2] = {};   // [dt], O^T fragments
  float lacc = 0.f;      // per-lane partial l (half the keys)

  // staging addresses: rows srow, 8-chunk scol, 16B XOR swizzle by row&7
  int srow0 = t >> 3, scol = t & 7;
  int srow1 = srow0 + 32;
  int sdst0 = srow0 * 64 + ((scol ^ (srow0 & 7)) * 8);
  int sdst1 = srow1 * 64 + ((scol ^ (srow1 & 7)) * 8);

  ushort8v kreg0, kreg1, vreg0, vreg1;
  {
    int kbase = (ks * NKB) * 64;
    kreg0 = *(const ushort8v*)(Qp + (size_t)(kbase + srow0) * DH + scol * 8);
    kreg1 = *(const ushort8v*)(Qp + (size_t)(kbase + srow1) * DH + scol * 8);
    vreg0 = *(const ushort8v*)(QTp + (size_t)srow0 * L_SEQ + kbase + scol * 8);
    vreg1 = *(const ushort8v*)(QTp + (size_t)srow1 * L_SEQ + kbase + scol * 8);
  }

  for (int kb = 0; kb < NKB; ++kb) {
    unsigned short* Kc = smem + (kb & 1) * 8192;
    unsigned short* Vc = Kc + 4096;
    // write buf[kb&1]: safe — its last readers (compute kb-2) are gated by
    // barrier(kb-1), which every wave passed before reaching this write.
    *(ushort8v*)(Kc + sdst0) = kreg0;
    *(ushort8v*)(Kc + sdst1) = kreg1;
    *(ushort8v*)(Vc + sdst0) = vreg0;
    *(ushort8v*)(Vc + sdst1) = vreg1;
    __syncthreads();
    if (kb + 1 < NKB) {  // issue next tile's loads; land during compute
      int kbase = (ks * NKB + kb + 1) * 64;
      kreg0 = *(const ushort8v*)(Qp + (size_t)(kbase + srow0) * DH + scol * 8);
      kreg1 = *(const ushort8v*)(Qp + (size_t)(kbase + srow1) * DH + scol * 8);
      vreg0 = *(const ushort8v*)(QTp + (size_t)srow0 * L_SEQ + kbase + scol * 8);
      vreg1 = *(const ushort8v*)(QTp + (size_t)srow1 * L_SEQ + kbase + scol * 8);
    }
#pragma unroll
    for (int mt = 0; mt < 2; ++mt) {
      int key = mt * 32 + ln;
      bf16x8 aK[4];
#pragma unroll
      for (int kq = 0; kq < 4; ++kq)
        aK[kq] = ld_frag(Kc + key * 64 + (((kq * 2 + hi) ^ (key & 7)) * 8));
      f32x16 s = {};
#pragma unroll
      for (int kq = 0; kq < 4; ++kq)
        s = __builtin_amdgcn_mfma_f32_32x32x16_bf16(aK[kq], aQ[kq], s, 0, 0, 0);
      // fixed-max softmax: p = exp(s/8 - 16); all 16 values same q
      float pv[16];
#pragma unroll
      for (int r = 0; r < 16; ++r) pv[r] = __expf(fmaf(s[r], 0.125f, -16.0f));
      lacc += (((pv[0] + pv[1]) + (pv[2] + pv[3])) + ((pv[4] + pv[5]) + (pv[6] + pv[7]))) +
              (((pv[8] + pv[9]) + (pv[10] + pv[11])) + ((pv[12] + pv[13]) + (pv[14] + pv[15])));
      // regs (0..15) -> keys (r&3)+8*(r>>2)+4*hi; pack + swap into B-frags
      unsigned w0 = cvtpk(pv[0], pv[1]), w1 = cvtpk(pv[2], pv[3]);
      unsigned w2 = cvtpk(pv[4], pv[5]), w3 = cvtpk(pv[6], pv[7]);
      unsigned w4 = cvtpk(pv[8], pv[9]), w5 = cvtpk(pv[10], pv[11]);
      unsigned w6 = cvtpk(pv[12], pv[13]), w7 = cvtpk(pv[14], pv[15]);
      plswap(w0, w2);  // after: w0 = keys{lo:0,1 | hi:8,9}, w2 = {lo:4,5 | hi:12,13}
      plswap(w1, w3);  //        w1 = {lo:2,3 | hi:10,11}, w3 = {lo:6,7 | hi:14,15}
      plswap(w4, w6);  // same for keys 16..31 (chunk 1)
      plswap(w5, w7);
      uint4v c0 = {w0, w1, w2, w3};
      uint4v c1 = {w4, w5, w6, w7};
      bf16x8 pf0 = __builtin_bit_cast(bf16x8, c0);
      bf16x8 pf1 = __builtin_bit_cast(bf16x8, c1);
      // ---- O^T += V^T P for this mt's 32 keys ----
#pragma unroll
      for (int dt = 0; dt < 2; ++dt) {
        int d = dt * 32 + ln;
        bf16x8 vf0 = ld_frag(Vc + d * 64 + (((mt * 4 + 0 * 2 + hi) ^ (d & 7)) * 8));
        bf16x8 vf1 = ld_frag(Vc + d * 64 + (((mt * 4 + 1 * 2 + hi) ^ (d & 7)) * 8));
        oacc[dt] = __builtin_amdgcn_mfma_f32_32x32x16_bf16(vf0, pf0, oacc[dt], 0, 0, 0);
        oacc[dt] = __builtin_amdgcn_mfma_f32_32x32x16_bf16(vf1, pf1, oacc[dt], 0, 0, 0);
      }
    }
  }
  // l: lanes l and l+32 hold same q, disjoint key halves
  lacc += __shfl_xor(lacc, 32, 64);
  size_t pq = (size_t)(ks * 8 + p) * L_SEQ;
  if (lane < 32) Lpart[pq + qw + ln] = lacc;
  // O^T epilogue (R1-verified pattern): lane owns q = qw+ln;
  // reg r -> d = dt*32 + (r>>2)*8 + hi*4 + (r&3); cvt_pk pairs -> 8B stores.
#pragma unroll
  for (int dt = 0; dt < 2; ++dt) {
    size_t rb = (pq + qw + ln) * DH + dt * 32 + hi * 4;
#pragma unroll
    for (int g8 = 0; g8 < 4; ++g8) {
      uint2v wv2 = {cvtpk(oacc[dt][g8 * 4 + 0], oacc[dt][g8 * 4 + 1]),
                    cvtpk(oacc[dt][g8 * 4 + 2], oacc[dt][g8 * 4 + 3])};
      *(uint2v*)(Opart + rb + g8 * 8) = wv2;
    }
  }
}

// ---- 4. FC GEMM (fused ks-merge in A-staging) + bias + residual + LayerNorm ----
#define CP 72
__global__ __launch_bounds__(256) void k_fc(const unsigned short* __restrict__ Opart,
                                            const float* __restrict__ Lpart,
                                            const unsigned short* __restrict__ fcwbf,
                                            const float* __restrict__ qres,
                                            const float* __restrict__ fcb,
                                            const float* __restrict__ lng,
                                            const float* __restrict__ lnb,
                                            float* __restrict__ out) {
  __shared__ unsigned short As[32 * CP];
  __shared__ unsigned short Bs[256 * CP];
  __shared__ float redS[4][32], redQ[4][32], muA[32], rsA[32];
  int bx = blockIdx.x;
  int m0 = bx * 32;
  int b = m0 >> 12, lpart = m0 & 4095;
  int t = threadIdx.x;
  int wv = t >> 6, lane = t & 63, g = lane >> 4, ln = lane & 15;
  f32x4 acc[2][4] = {};
  for (int kb = 0; kb < 4; ++kb) {   // kb == head index for A-staging
    {
      int row = t >> 3, c0 = (t & 7) * 8;
      int q = lpart + row;
      int p = b * 4 + kb;
      float lsum = Lpart[(size_t)(0 * 8 + p) * L_SEQ + q] +
                   Lpart[(size_t)(1 * 8 + p) * L_SEQ + q] +
                   Lpart[(size_t)(2 * 8 + p) * L_SEQ + q] +
                   Lpart[(size_t)(3 * 8 + p) * L_SEQ + q];
      float inv = 1.0f / lsum;
      float a8[8] = {0.f, 0.f, 0.f, 0.f, 0.f, 0.f, 0.f, 0.f};
#pragma unroll
      for (int ksp = 0; ksp < 4; ++ksp) {
        ushort8v v = *(const ushort8v*)(Opart + ((size_t)(ksp * 8 + p) * L_SEQ + q) * DH + c0);
#pragma unroll
        for (int j = 0; j < 8; ++j) a8[j] += bf2f(v[j]);
      }
      ushort8v o;
#pragma unroll
      for (int j = 0; j < 8; ++j) o[j] = f2bf(a8[j] * inv);
      *(ushort8v*)(As + row * CP + c0) = o;
    }
#pragma unroll
    for (int it = 0; it < 8; ++it) {
      int idx = t + it * 256;
      int row = idx >> 3, c0 = (idx & 7) * 8;
      *(ushort8v*)(Bs + row * CP + c0) =
          *(const ushort8v*)(fcwbf + (size_t)row * 256 + kb * 64 + c0);
    }
    __syncthreads();
#pragma unroll
    for (int kc = 0; kc < 2; ++kc) {
      bf16x8 a[2], bb[4];
#pragma unroll
      for (int mt = 0; mt < 2; ++mt) a[mt] = ld_frag(As + (mt * 16 + ln) * CP + kc * 32 + g * 8);
#pragma unroll
      for (int tn = 0; tn < 4; ++tn) bb[tn] = ld_frag(Bs + (wv * 64 + tn * 16 + ln) * CP + kc * 32 + g * 8);
#pragma unroll
      for (int mt = 0; mt < 2; ++mt)
#pragma unroll
        for (int tn = 0; tn < 4; ++tn)
          acc[mt][tn] = __builtin_amdgcn_mfma_f32_16x16x32_bf16(a[mt], bb[tn], acc[mt][tn], 0, 0, 0);
    }
    __syncthreads();
  }
  float fb[4], lg[4], lb[4];
#pragma unroll
  for (int tn = 0; tn < 4; ++tn) {
    int o = wv * 64 + tn * 16 + ln;
    fb[tn] = fcb[o]; lg[tn] = lng[o]; lb[tn] = lnb[o];
  }
#pragma unroll
  for (int mt = 0; mt < 2; ++mt) {
    float ps[4] = {0.f, 0.f, 0.f, 0.f}, pq2[4] = {0.f, 0.f, 0.f, 0.f};
#pragma unroll
    for (int tn = 0; tn < 4; ++tn) {
      int o = wv * 64 + tn * 16 + ln;
      float4 res = *(const float4*)(qres + ((size_t)(b * 256 + o)) * 4096 + lpart + mt * 16 + g * 4);
      float rv[4] = {res.x, res.y, res.z, res.w};
#pragma unroll
      for (int r = 0; r < 4; ++r) {
        float v = acc[mt][tn][r] + fb[tn] + rv[r];
        acc[mt][tn][r] = v;
        ps[r] += v;
        pq2[r] += v * v;
      }
    }
#pragma unroll
    for (int r = 0; r < 4; ++r) {
      float s = ps[r], q2 = pq2[r];
#pragma unroll
      for (int off = 1; off < 16; off <<= 1) {
        s += __shfl_xor(s, off, 64);
        q2 += __shfl_xor(q2, off, 64);
      }
      if (ln == 0) {
        int row = mt * 16 + g * 4 + r;
        redS[wv][row] = s;
        redQ[wv][row] = q2;
      }
    }
  }
  __syncthreads();
  if (t < 32) {
    float s = redS[0][t] + redS[1][t] + redS[2][t] + redS[3][t];
    float q2 = redQ[0][t] + redQ[1][t] + redQ[2][t] + redQ[3][t];
    float mu = s * (1.f / 256.f);
    float var = q2 * (1.f / 256.f) - mu * mu;
    muA[t] = mu;
    rsA[t] = rsqrtf(var + 1e-5f);
  }
  __syncthreads();
#pragma unroll
  for (int mt = 0; mt < 2; ++mt) {
#pragma unroll
    for (int r = 0; r < 4; ++r) {
      int row = mt * 16 + g * 4 + r;
      float mu = muA[row], rs = rsA[row];
#pragma unroll
      for (int tn = 0; tn < 4; ++tn) {
        int o = wv * 64 + tn * 16 + ln;
        out[(size_t)(m0 + row) * 256 + o] = (acc[mt][tn][r] - mu) * rs * lg[tn] + lb[tn];
      }
    }
  }
}

extern "C" void kernel_launch(void* const* d_in, const int* in_sizes, int n_in,
                              void* d_out, int out_size, void* d_ws, size_t ws_size,
                              hipStream_t stream) {
  const float* q = (const float*)d_in[0];
  const float* w_qkv = (const float*)d_in[1];
  const float* fc_w = (const float*)d_in[2];
  const float* fc_b = (const float*)d_in[3];
  const float* ln_g = (const float*)d_in[4];
  const float* ln_b = (const float*)d_in[5];
  float* out = (float*)d_out;

  unsigned short* wbf = (unsigned short*)d_ws;   // 65536
  unsigned short* fcwbf = wbf + 65536;           // 65536
  unsigned short* xbf = fcwbf + 65536;           // 8192*256
  unsigned short* Qh = xbf + 2097152;            // [p][l][d]
  unsigned short* QhT = Qh + 2097152;            // [p][d][l]
  unsigned short* Opart = QhT + 2097152;         // [ks][p][q][d] bf16, 4*2M
  float* Lpart = (float*)(Opart + 8388608);      // [ks][p][q] fp32
  // total ws use: ~30.1 MB

  k_transpose<<<dim3(576), dim3(256), 0, stream>>>(q, xbf, w_qkv, fc_w, wbf, fcwbf);
  k_qkv<<<dim3(512), dim3(256), 0, stream>>>(xbf, wbf, Qh, QhT);
  k_attn<<<dim3(1024), dim3(256), 0, stream>>>(Qh, QhT, Opart, Lpart);
  k_fc<<<dim3(256), dim3(256), 0, stream>>>(Opart, Lpart, fcwbf, q, fc_b, ln_g, ln_b, out);
}